// Round 11
// baseline (103.165 us; speedup 1.0000x reference)
//
#include <hip/hip_runtime.h>

#define NROWS 8192
#define NCOLS 4096
#define LAMB  0.1

typedef unsigned int u32;
typedef unsigned long long u64;

// ---------------------------------------------------------------------------
// Kernel 1: per-row squared error sum. ONE 256-THREAD BLOCK PER ROW.
// BYTE-IDENTICAL to R10 (control for this round's measurement).
// ---------------------------------------------------------------------------
__global__ __launch_bounds__(256) void rowerr_kernel(const float* __restrict__ inp,
                                                     const float* __restrict__ tgt,
                                                     float* __restrict__ err) {
    const int row = blockIdx.x;
    const float4* a = reinterpret_cast<const float4*>(inp + (size_t)row * NCOLS);
    const float4* b = reinterpret_cast<const float4*>(tgt + (size_t)row * NCOLS);
    const int t = threadIdx.x;

    float acc = 0.f;
#pragma unroll
    for (int c = 0; c < 4; ++c) {
        float4 va = a[t + c * 256];
        float4 vb = b[t + c * 256];
        float dx = va.x - vb.x;
        float dy = va.y - vb.y;
        float dz = va.z - vb.z;
        float dw = va.w - vb.w;
        acc += dx * dx + dy * dy + dz * dz + dw * dw;
    }

    // wave (64-lane) reduce
#pragma unroll
    for (int off = 32; off > 0; off >>= 1) acc += __shfl_down(acc, off, 64);

    __shared__ float ws[4];
    const int lane = t & 63, wv = t >> 6;
    if (lane == 0) ws[wv] = acc;
    __syncthreads();
    if (t == 0) err[row] = ws[0] + ws[1] + ws[2] + ws[3];
}

// ---------------------------------------------------------------------------
// fast f64 reciprocal: f32 seed + 2 Newton steps (~1 ulp, no f64 divide)
// ---------------------------------------------------------------------------
__device__ __forceinline__ double fastrcp(double x) {
    double r = (double)(1.0f / (float)x);
    r = r * (2.0 - x * r);
    r = r * (2.0 - x * r);
    return r;
}

// ---------------------------------------------------------------------------
// Kernel 2: single block, 1024 threads (16 waves), LSD RADIX-256 sort in LDS
// + fused obj phase. BYTE-IDENTICAL to R10.
// THIS ROUND: launched TWICE (idempotent) — the bench-time delta vs R10's
// 74.0 us measures this kernel's true in-bench cost (launch gap included).
// ---------------------------------------------------------------------------
__global__ __launch_bounds__(1024) void drae_kernel(const float* __restrict__ err,
                                                    float* __restrict__ out) {
    const int N = NROWS;
    __shared__ u32 bufA[NROWS];          // 32 KB
    __shared__ u32 bufB[NROWS];          // 32 KB
    __shared__ u32 hist[16 * 256];       // 16 KB
    __shared__ u32 dtot[256], dbase[256];
    __shared__ u32 saux[4];
    __shared__ double auxX[16], auxT2[16], redH[16], redCs[16];
    __shared__ int    redIdx[16];

    const int tid  = threadIdx.x;
    const int lane = tid & 63, wv = tid >> 6;
    const u64 ltmask = (1ull << lane) - 1ull;

    // ---- stage float bits into LDS (coalesced) ----
#pragma unroll
    for (int k = 0; k < 8; ++k) {
        const int i = tid + k * 1024;
        bufA[i] = __float_as_uint(err[i]);
    }

    u32* src = bufA;
    u32* dst = bufB;

    for (int pass = 0; pass < 4; ++pass) {
        const int shift = pass * 8;

        __syncthreads();                       // prev scatter / staging visible
#pragma unroll
        for (int k = 0; k < 4; ++k) hist[tid + k * 1024] = 0;
        __syncthreads();                       // hist zeroed

        // ---- read keys (strided: array idx = wv*512 + r*64 + lane) ----
        u32 key[8], rnk[8];
#pragma unroll
        for (int r = 0; r < 8; ++r) key[r] = src[wv * 512 + r * 64 + lane];

        // ---- ballot multi-split: rank within (wave, digit), array order ----
#pragma unroll
        for (int r = 0; r < 8; ++r) {
            const u32 d = (key[r] >> shift) & 255u;
            u64 match = ~0ull;
#pragma unroll
            for (int b = 0; b < 8; ++b) {
                const u64 bb = __ballot((d >> b) & 1u);
                match &= ((d >> b) & 1u) ? bb : ~bb;
            }
            const int within = __popcll(match & ltmask);
            const int leader = __builtin_ctzll(match);      // match != 0 (self)
            const u32 base = hist[wv * 256 + d];            // group broadcast
            rnk[r] = base + (u32)within;
            if (lane == leader) hist[wv * 256 + d] = base + (u32)__popcll(match);
        }
        __syncthreads();                       // all wave histograms complete

        // ---- per-digit column scan over waves; dtot[d] = digit total ----
        if (tid < 256) {
            u32 s = 0;
#pragma unroll
            for (int w = 0; w < 16; ++w) {
                const u32 t = hist[w * 256 + tid];
                hist[w * 256 + tid] = s;       // exclusive over waves
                s += t;
            }
            dtot[tid] = s;
        }
        __syncthreads();

        // ---- exclusive scan of dtot[256] -> dbase ----
        u32 val = 0, incl = 0;
        if (tid < 256) {
            val  = dtot[tid];
            incl = val;
#pragma unroll
            for (int off = 1; off < 64; off <<= 1) {
                const u32 t = __shfl_up(incl, off, 64);
                if (lane >= off) incl += t;
            }
            if (lane == 63) saux[wv] = incl;   // wv in 0..3 here
        }
        __syncthreads();
        if (tid < 256) {
            u32 add = 0;
#pragma unroll
            for (int w = 0; w < 4; ++w) if (w < wv) add += saux[w];
            dbase[tid] = incl - val + add;
        }
        __syncthreads();

        // ---- stable scatter ----
#pragma unroll
        for (int r = 0; r < 8; ++r) {
            const u32 d = (key[r] >> shift) & 255u;
            dst[dbase[d] + hist[wv * 256 + d] + rnk[r]] = key[r];
        }

        u32* tmp = src; src = dst; dst = tmp;  // A->B->A->B->A
    }
    __syncthreads();                           // src (==bufA) fully sorted

    // ================= obj phase (same block) ==============================
    float v[8];
#pragma unroll
    for (int r = 0; r < 8; ++r) v[r] = __uint_as_float(src[(tid << 3) + r]);

    double sx = 0.0, sx2 = 0.0;
#pragma unroll
    for (int r = 0; r < 8; ++r) {
        sx  += (double)v[r];
        sx2 += (double)v[r] * (double)v[r];
    }

    // wave inclusive scan of sx; wave total of sx2
    double ix = sx;
#pragma unroll
    for (int off = 1; off < 64; off <<= 1) {
        double t1 = __shfl_up(ix, off, 64);
        if (lane >= off) ix += t1;
    }
    double t2 = sx2;
#pragma unroll
    for (int off = 32; off > 0; off >>= 1) t2 += __shfl_xor(t2, off, 64);

    if (lane == 63) auxX[wv]  = ix;
    if (lane == 0)  auxT2[wv] = t2;
    __syncthreads();

    double wOff1 = 0.0, total1 = 0.0, total2 = 0.0;
#pragma unroll
    for (int w = 0; w < 16; ++w) {
        const double a1 = auxX[w];
        if (w < wv) wOff1 += a1;
        total1 += a1;
        total2 += auxT2[w];
    }
    const double exc1 = wOff1 + (ix - sx);   // exclusive prefix before this chunk
    const double nf = (double)N;

    // on-the-fly h(k) + local argmax (== argmin obj), first index on ties
    double run1 = exc1;
    double bestH = -1e300, bestCs = 0.0;
    int bestIdx = N;
#pragma unroll
    for (int r = 0; r < 8; ++r) {
        const int idx = (tid << 3) + r;
        run1 += (double)v[r];
        if (idx < N - 1) {
            const double kf  = (double)(idx + 1);
            const double rem = total1 - run1;
            const double h   = run1 * run1 * fastrcp(kf) +
                               rem  * rem  * fastrcp(nf - kf);
            if (h > bestH) { bestH = h; bestIdx = idx; bestCs = run1; }
        }
    }

    // wave argmax reduce (max h, first index on ties)
#pragma unroll
    for (int off = 32; off > 0; off >>= 1) {
        const double oH   = __shfl_down(bestH, off, 64);
        const int    oIdx = __shfl_down(bestIdx, off, 64);
        const double oCs  = __shfl_down(bestCs, off, 64);
        if (oH > bestH || (oH == bestH && oIdx < bestIdx)) {
            bestH = oH; bestIdx = oIdx; bestCs = oCs;
        }
    }
    if (lane == 0) { redH[wv] = bestH; redIdx[wv] = bestIdx; redCs[wv] = bestCs; }
    __syncthreads();

    if (tid == 0) {
        double bH = redH[0], bCs = redCs[0];
        int bIdx = redIdx[0];
        for (int w = 1; w < 16; ++w) {
            if (redH[w] > bH || (redH[w] == bH && redIdx[w] < bIdx)) {
                bH = redH[w]; bIdx = redIdx[w]; bCs = redCs[w];
            }
        }
        const double Sb     = total2 - total1 * total1 / nf;
        const double optObj = (total2 - bH) / Sb;
        const double T      = (double)(bIdx + 1);
        out[0] = (float)(bCs / T + LAMB * optObj);
    }
}

// ---------------------------------------------------------------------------
extern "C" void kernel_launch(void* const* d_in, const int* in_sizes, int n_in,
                              void* d_out, int out_size, void* d_ws, size_t ws_size,
                              hipStream_t stream) {
    const float* inp = (const float*)d_in[0];
    const float* tgt = (const float*)d_in[1];
    float* errbuf = (float*)d_ws;   // 8192 f32 = 32 KB scratch

    rowerr_kernel<<<NROWS, 256, 0, stream>>>(inp, tgt, errbuf);
    // MEASUREMENT: drae launched twice (idempotent). Bench delta vs R10's
    // 74.0 us == true in-bench cost of one drae dispatch (incl. launch gap).
    drae_kernel<<<1, 1024, 0, stream>>>(errbuf, (float*)d_out);
    drae_kernel<<<1, 1024, 0, stream>>>(errbuf, (float*)d_out);
}

// Round 12
// 86.060 us; speedup vs baseline: 1.1988x; 1.1988x over previous
//
#include <hip/hip_runtime.h>

#define NROWS 8192
#define NCOLS 4096
#define LAMB  0.1
#define NBLK  512
#define RPB   16    // rows per block (one per wave)

typedef unsigned int u32;
typedef unsigned short u16;
typedef unsigned long long u64;

// ---------------------------------------------------------------------------
// fast f64 reciprocal: f32 seed + 2 Newton steps (~1 ulp, no f64 divide)
// ---------------------------------------------------------------------------
__device__ __forceinline__ double fastrcp(double x) {
    double r = (double)(1.0f / (float)x);
    r = r * (2.0 - x * r);
    r = r * (2.0 - x * r);
    return r;
}

// ---------------------------------------------------------------------------
// FUSED kernel: 512 blocks x 1024 threads.
// Phase A (all blocks): wave-per-row squared-error sums; err written via
//   AGENT-scope atomic stores (write-through -> coherent point; NO wbl2).
// Ticket: ACQ_REL atomicAdd; 511 blocks exit; last block runs the tail.
// Tail (1 block): stage err (AGENT loads) -> LDS, subtract-min radix-256
//   (3 passes if key range < 2^24, else 4), f64 scan + h(k) argmax, out.
//   h(k) = cs^2/k + (total-cs)^2/(n-k); argmax h == argmin (Sw1+Sw2)/Sb.
// LDS ~76.5 KB -> 2 blocks/CU during phase A.
// ---------------------------------------------------------------------------
__global__ __launch_bounds__(1024) void fused_kernel(const float* __restrict__ inp,
                                                     const float* __restrict__ tgt,
                                                     float* err, u32* counter,
                                                     float* __restrict__ out) {
    const int N = NROWS;
    __shared__ u32 bufA[NROWS];          // 32 KB
    __shared__ u32 bufB[NROWS];          // 32 KB
    __shared__ u16 hist[16 * 256];       // 8 KB
    __shared__ u32 dtot[256], dbase[256];
    __shared__ u32 saux[4];
    __shared__ u32 sMin[16], sMax[16];
    __shared__ double auxX[16], auxT2[16], redH[16], redCs[16];
    __shared__ int    redIdx[16];
    __shared__ int    amLast;

    const int tid  = threadIdx.x;
    const int lane = tid & 63, wv = tid >> 6;
    const u64 ltmask = (1ull << lane) - 1ull;

    // ================= phase A: rowerr (one wave per row) ==================
    {
        const int row = blockIdx.x * RPB + wv;
        const float4* a = reinterpret_cast<const float4*>(inp + (size_t)row * NCOLS);
        const float4* b = reinterpret_cast<const float4*>(tgt + (size_t)row * NCOLS);

        float a0 = 0.f, a1 = 0.f, a2 = 0.f, a3 = 0.f;
#pragma unroll
        for (int c = 0; c < 16; ++c) {
            const float4 va = a[lane + c * 64];
            const float4 vb = b[lane + c * 64];
            const float dx = va.x - vb.x;
            const float dy = va.y - vb.y;
            const float dz = va.z - vb.z;
            const float dw = va.w - vb.w;
            a0 += dx * dx; a1 += dy * dy; a2 += dz * dz; a3 += dw * dw;
        }
        float acc = (a0 + a1) + (a2 + a3);
#pragma unroll
        for (int off = 32; off > 0; off >>= 1) acc += __shfl_down(acc, off, 64);

        if (lane == 0)
            __hip_atomic_store(&err[row], acc, __ATOMIC_RELAXED,
                               __HIP_MEMORY_SCOPE_AGENT);
    }

    // ================= ticket ==============================================
    __syncthreads();   // compiler drains vmcnt before barrier -> stores done
    if (tid == 0) {
        const u32 old = __hip_atomic_fetch_add(counter, 1u, __ATOMIC_ACQ_REL,
                                               __HIP_MEMORY_SCOPE_AGENT);
        amLast = (old == (u32)(NBLK - 1));
    }
    __syncthreads();
    if (!amLast) return;

    // ================= tail: stage + min/max ===============================
    u32 bits[8];
    u32 mn = 0xFFFFFFFFu, mx = 0u;
#pragma unroll
    for (int k = 0; k < 8; ++k) {
        const int i = tid + k * 1024;
        const float v = __hip_atomic_load(&err[i], __ATOMIC_RELAXED,
                                          __HIP_MEMORY_SCOPE_AGENT);
        bits[k] = __float_as_uint(v);
        mn = min(mn, bits[k]);
        mx = max(mx, bits[k]);
    }
#pragma unroll
    for (int off = 32; off > 0; off >>= 1) {
        mn = min(mn, (u32)__shfl_xor((int)mn, off, 64));
        mx = max(mx, (u32)__shfl_xor((int)mx, off, 64));
    }
    if (lane == 0) { sMin[wv] = mn; sMax[wv] = mx; }
    __syncthreads();
    u32 minb = sMin[0], maxb = sMax[0];
#pragma unroll
    for (int w = 1; w < 16; ++w) { minb = min(minb, sMin[w]); maxb = max(maxb, sMax[w]); }
    const int npass = ((maxb - minb) < (1u << 24)) ? 3 : 4;

#pragma unroll
    for (int k = 0; k < 8; ++k) bufA[tid + k * 1024] = bits[k] - minb;

    u32* src = bufA;
    u32* dst = bufB;

    // ================= LSD radix-256 sort in LDS ===========================
    for (int pass = 0; pass < npass; ++pass) {
        const int shift = pass * 8;

        __syncthreads();                       // prev scatter / staging visible
        {   // zero u16 hist via u32 writes
            u32* h32 = reinterpret_cast<u32*>(hist);
            h32[tid] = 0; h32[tid + 1024] = 0;
        }
        __syncthreads();

        // read keys (strided: array idx = wv*512 + r*64 + lane)
        u32 key[8], rnk[8];
#pragma unroll
        for (int r = 0; r < 8; ++r) key[r] = src[wv * 512 + r * 64 + lane];

        // ballot multi-split: rank within (wave, digit), array order
#pragma unroll
        for (int r = 0; r < 8; ++r) {
            const u32 d = (key[r] >> shift) & 255u;
            u64 match = ~0ull;
#pragma unroll
            for (int b = 0; b < 8; ++b) {
                const u64 bb = __ballot((d >> b) & 1u);
                match &= ((d >> b) & 1u) ? bb : ~bb;
            }
            const int within = __popcll(match & ltmask);
            const int leader = __builtin_ctzll(match);
            const u32 base = (u32)hist[wv * 256 + d];
            rnk[r] = base + (u32)within;
            if (lane == leader) hist[wv * 256 + d] = (u16)(base + (u32)__popcll(match));
        }
        __syncthreads();

        // per-digit column scan over waves; dtot[d] = digit total
        if (tid < 256) {
            u32 s = 0;
#pragma unroll
            for (int w = 0; w < 16; ++w) {
                const u32 t = (u32)hist[w * 256 + tid];
                hist[w * 256 + tid] = (u16)s;
                s += t;
            }
            dtot[tid] = s;
        }
        __syncthreads();

        // exclusive scan of dtot[256] -> dbase
        u32 val = 0, incl = 0;
        if (tid < 256) {
            val  = dtot[tid];
            incl = val;
#pragma unroll
            for (int off = 1; off < 64; off <<= 1) {
                const u32 t = __shfl_up(incl, off, 64);
                if (lane >= off) incl += t;
            }
            if (lane == 63) saux[wv] = incl;   // wv in 0..3 here
        }
        __syncthreads();
        if (tid < 256) {
            u32 add = 0;
#pragma unroll
            for (int w = 0; w < 4; ++w) if (w < wv) add += saux[w];
            dbase[tid] = incl - val + add;
        }
        __syncthreads();

        // stable scatter
#pragma unroll
        for (int r = 0; r < 8; ++r) {
            const u32 d = (key[r] >> shift) & 255u;
            dst[dbase[d] + (u32)hist[wv * 256 + d] + rnk[r]] = key[r];
        }

        u32* tmp = src; src = dst; dst = tmp;
    }
    __syncthreads();                           // src fully sorted (biased keys)

    // ================= obj phase ==========================================
    float v[8];
#pragma unroll
    for (int r = 0; r < 8; ++r) v[r] = __uint_as_float(src[(tid << 3) + r] + minb);

    double sx = 0.0, sx2 = 0.0;
#pragma unroll
    for (int r = 0; r < 8; ++r) {
        sx  += (double)v[r];
        sx2 += (double)v[r] * (double)v[r];
    }

    // wave inclusive scan of sx; wave total of sx2
    double ix = sx;
#pragma unroll
    for (int off = 1; off < 64; off <<= 1) {
        double t1 = __shfl_up(ix, off, 64);
        if (lane >= off) ix += t1;
    }
    double t2 = sx2;
#pragma unroll
    for (int off = 32; off > 0; off >>= 1) t2 += __shfl_xor(t2, off, 64);

    if (lane == 63) auxX[wv]  = ix;
    if (lane == 0)  auxT2[wv] = t2;
    __syncthreads();

    double wOff1 = 0.0, total1 = 0.0, total2 = 0.0;
#pragma unroll
    for (int w = 0; w < 16; ++w) {
        const double a1 = auxX[w];
        if (w < wv) wOff1 += a1;
        total1 += a1;
        total2 += auxT2[w];
    }
    const double exc1 = wOff1 + (ix - sx);
    const double nf = (double)N;

    // on-the-fly h(k) + local argmax (== argmin obj), first index on ties
    double run1 = exc1;
    double bestH = -1e300, bestCs = 0.0;
    int bestIdx = N;
#pragma unroll
    for (int r = 0; r < 8; ++r) {
        const int idx = (tid << 3) + r;
        run1 += (double)v[r];
        if (idx < N - 1) {
            const double kf  = (double)(idx + 1);
            const double rem = total1 - run1;
            const double h   = run1 * run1 * fastrcp(kf) +
                               rem  * rem  * fastrcp(nf - kf);
            if (h > bestH) { bestH = h; bestIdx = idx; bestCs = run1; }
        }
    }

    // wave argmax reduce (max h, first index on ties)
#pragma unroll
    for (int off = 32; off > 0; off >>= 1) {
        const double oH   = __shfl_down(bestH, off, 64);
        const int    oIdx = __shfl_down(bestIdx, off, 64);
        const double oCs  = __shfl_down(bestCs, off, 64);
        if (oH > bestH || (oH == bestH && oIdx < bestIdx)) {
            bestH = oH; bestIdx = oIdx; bestCs = oCs;
        }
    }
    if (lane == 0) { redH[wv] = bestH; redIdx[wv] = bestIdx; redCs[wv] = bestCs; }
    __syncthreads();

    if (tid == 0) {
        double bH = redH[0], bCs = redCs[0];
        int bIdx = redIdx[0];
        for (int w = 1; w < 16; ++w) {
            if (redH[w] > bH || (redH[w] == bH && redIdx[w] < bIdx)) {
                bH = redH[w]; bIdx = redIdx[w]; bCs = redCs[w];
            }
        }
        const double Sb     = total2 - total1 * total1 / nf;
        const double optObj = (total2 - bH) / Sb;
        const double T      = (double)(bIdx + 1);
        out[0] = (float)(bCs / T + LAMB * optObj);
    }
}

// ---------------------------------------------------------------------------
extern "C" void kernel_launch(void* const* d_in, const int* in_sizes, int n_in,
                              void* d_out, int out_size, void* d_ws, size_t ws_size,
                              hipStream_t stream) {
    const float* inp = (const float*)d_in[0];
    const float* tgt = (const float*)d_in[1];
    float* errbuf = (float*)d_ws;                       // 8192 f32 = 32 KB
    u32*   counter = (u32*)((char*)d_ws + NROWS * 4);   // 4 B ticket

    hipMemsetAsync(counter, 0, 4, stream);              // graph-legal init
    fused_kernel<<<NBLK, 1024, 0, stream>>>(inp, tgt, errbuf, counter,
                                            (float*)d_out);
}

// Round 13
// 67.059 us; speedup vs baseline: 1.5384x; 1.2834x over previous
//
#include <hip/hip_runtime.h>

#define NROWS 8192
#define NCOLS 4096
#define LAMB  0.1
#define NBUCK 2048

typedef unsigned int u32;
typedef unsigned long long u64;

// ---------------------------------------------------------------------------
// Kernel 1: per-row squared error sum. ONE 256-THREAD BLOCK PER ROW.
// Byte-identical to R10 (best measured: ~41 us in-bench, warm L3).
// ---------------------------------------------------------------------------
__global__ __launch_bounds__(256) void rowerr_kernel(const float* __restrict__ inp,
                                                     const float* __restrict__ tgt,
                                                     float* __restrict__ err) {
    const int row = blockIdx.x;
    const float4* a = reinterpret_cast<const float4*>(inp + (size_t)row * NCOLS);
    const float4* b = reinterpret_cast<const float4*>(tgt + (size_t)row * NCOLS);
    const int t = threadIdx.x;

    float acc = 0.f;
#pragma unroll
    for (int c = 0; c < 4; ++c) {
        float4 va = a[t + c * 256];
        float4 vb = b[t + c * 256];
        float dx = va.x - vb.x;
        float dy = va.y - vb.y;
        float dz = va.z - vb.z;
        float dw = va.w - vb.w;
        acc += dx * dx + dy * dy + dz * dz + dw * dw;
    }

#pragma unroll
    for (int off = 32; off > 0; off >>= 1) acc += __shfl_down(acc, off, 64);

    __shared__ float ws[4];
    const int lane = t & 63, wv = t >> 6;
    if (lane == 0) ws[wv] = acc;
    __syncthreads();
    if (t == 0) err[row] = ws[0] + ws[1] + ws[2] + ws[3];
}

// ---------------------------------------------------------------------------
// fast f64 reciprocal: f32 seed + 2 Newton steps (~1 ulp, no f64 divide)
// ---------------------------------------------------------------------------
__device__ __forceinline__ double fastrcp(double x) {
    double r = (double)(1.0f / (float)x);
    r = r * (2.0 - x * r);
    r = r * (2.0 - x * r);
    return r;
}

// ---------------------------------------------------------------------------
// Kernel 2: single block, 1024 threads. BUCKET SORT + EXACT RANK (replaces
// radix): keys = float bits - min (monotone, all err >= 0). bucket =
// (key >> shift) with shift sized so top bits of the range give < 2048
// buckets (avg ~4 elems each for this data).
//   1. LDS-atomic histogram (8 adds/thread)
//   2. exclusive scan of 2048 counts (2 buckets/thread, wave scans)
//   3. scatter via atomic cursor; returned offset = tie-break order
//   4. exact rank: each element counts (smaller) or (equal, earlier) over
//      its bucket segment -- short independent LDS reads, no dep chains
//   5. fused obj phase: f64 scan of cs, total of cs2, argmax of
//      h(k) = cs^2/k + (total-cs)^2/(n-k)  (== argmin (Sw1+Sw2)/Sb)
// Exact permutation for ANY input (degenerate inputs just run slower).
// ---------------------------------------------------------------------------
__global__ __launch_bounds__(1024) void drae_kernel(const float* __restrict__ err,
                                                    float* __restrict__ out) {
    const int N = NROWS;
    __shared__ u32 bufS[NROWS];            // 32 KB  sorted output
    __shared__ u32 bufB[NROWS];            // 32 KB  scattered (bucket-grouped)
    __shared__ u32 hist[NBUCK];            // 8 KB   counts -> cursors
    __shared__ u32 base2[NBUCK];           // 8 KB   segment starts
    __shared__ u32 cnt2[NBUCK];            // 8 KB   segment lengths
    __shared__ u32 sMin[16], sMax[16], saux[16];
    __shared__ double auxX[16], auxT2[16], redH[16], redCs[16];
    __shared__ int    redIdx[16];

    const int tid  = threadIdx.x;
    const int lane = tid & 63, wv = tid >> 6;

    // ---- stage to regs + min/max ----
    u32 bits[8];
    u32 mn = 0xFFFFFFFFu, mx = 0u;
#pragma unroll
    for (int k = 0; k < 8; ++k) {
        bits[k] = __float_as_uint(err[tid + k * 1024]);
        mn = min(mn, bits[k]);
        mx = max(mx, bits[k]);
    }
#pragma unroll
    for (int off = 32; off > 0; off >>= 1) {
        mn = min(mn, (u32)__shfl_xor((int)mn, off, 64));
        mx = max(mx, (u32)__shfl_xor((int)mx, off, 64));
    }
    if (lane == 0) { sMin[wv] = mn; sMax[wv] = mx; }

    // zero histogram while min/max settles
    hist[tid] = 0;
    hist[tid + 1024] = 0;
    __syncthreads();

    u32 minb = sMin[0], maxb = sMax[0];
#pragma unroll
    for (int w = 1; w < 16; ++w) { minb = min(minb, sMin[w]); maxb = max(maxb, sMax[w]); }
    const u32 range = maxb - minb;
    const int nbits = 32 - __clz(range | 1u);          // >=1
    const int shift = (nbits > 11) ? (nbits - 11) : 0; // bucket < 2048

    u32 bk[8];
#pragma unroll
    for (int k = 0; k < 8; ++k) {
        bits[k] -= minb;
        bk[k] = bits[k] >> shift;
        atomicAdd(&hist[bk[k]], 1u);
    }
    __syncthreads();

    // ---- exclusive scan of 2048 counts (2 per thread) ----
    const u32 c0 = hist[2 * tid], c1 = hist[2 * tid + 1];
    const u32 tsum = c0 + c1;
    u32 incl = tsum;
#pragma unroll
    for (int off = 1; off < 64; off <<= 1) {
        const u32 t = __shfl_up(incl, off, 64);
        if (lane >= off) incl += t;
    }
    if (lane == 63) saux[wv] = incl;
    __syncthreads();                       // also: all hist reads done
    u32 add = 0;
#pragma unroll
    for (int w = 0; w < 16; ++w) if (w < wv) add += saux[w];
    const u32 excl = add + incl - tsum;
    base2[2 * tid] = excl;           base2[2 * tid + 1] = excl + c0;
    cnt2[2 * tid]  = c0;             cnt2[2 * tid + 1]  = c1;
    hist[2 * tid]  = excl;           hist[2 * tid + 1]  = excl + c0;   // cursors
    __syncthreads();

    // ---- scatter; atomic cursor return = tie-break order within bucket ----
    u32 myq[8];
#pragma unroll
    for (int k = 0; k < 8; ++k) {
        const u32 p = atomicAdd(&hist[bk[k]], 1u);
        myq[k] = p - base2[bk[k]];
        bufB[p] = bits[k];
    }
    __syncthreads();

    // ---- exact rank within bucket (independent LDS reads, short loops) ----
#pragma unroll
    for (int k = 0; k < 8; ++k) {
        const u32 s = base2[bk[k]];
        const u32 c = cnt2[bk[k]];
        const u32 ki = bits[k];
        u32 r = 0;
        for (u32 q = 0; q < c; ++q) {
            const u32 v = bufB[s + q];
            r += (v < ki || (v == ki && q < myq[k])) ? 1u : 0u;
        }
        bufS[s + r] = ki;
    }
    __syncthreads();                       // bufS fully sorted (biased keys)

    // ================= obj phase ==========================================
    float v[8];
#pragma unroll
    for (int r = 0; r < 8; ++r) v[r] = __uint_as_float(bufS[(tid << 3) + r] + minb);

    double sx = 0.0, sx2 = 0.0;
#pragma unroll
    for (int r = 0; r < 8; ++r) {
        sx  += (double)v[r];
        sx2 += (double)v[r] * (double)v[r];
    }

    // wave inclusive scan of sx; wave total of sx2
    double ix = sx;
#pragma unroll
    for (int off = 1; off < 64; off <<= 1) {
        double t1 = __shfl_up(ix, off, 64);
        if (lane >= off) ix += t1;
    }
    double t2 = sx2;
#pragma unroll
    for (int off = 32; off > 0; off >>= 1) t2 += __shfl_xor(t2, off, 64);

    if (lane == 63) auxX[wv]  = ix;
    if (lane == 0)  auxT2[wv] = t2;
    __syncthreads();

    double wOff1 = 0.0, total1 = 0.0, total2 = 0.0;
#pragma unroll
    for (int w = 0; w < 16; ++w) {
        const double a1 = auxX[w];
        if (w < wv) wOff1 += a1;
        total1 += a1;
        total2 += auxT2[w];
    }
    const double exc1 = wOff1 + (ix - sx);
    const double nf = (double)N;

    // on-the-fly h(k) + local argmax (== argmin obj), first index on ties
    double run1 = exc1;
    double bestH = -1e300, bestCs = 0.0;
    int bestIdx = N;
#pragma unroll
    for (int r = 0; r < 8; ++r) {
        const int idx = (tid << 3) + r;
        run1 += (double)v[r];
        if (idx < N - 1) {
            const double kf  = (double)(idx + 1);
            const double rem = total1 - run1;
            const double h   = run1 * run1 * fastrcp(kf) +
                               rem  * rem  * fastrcp(nf - kf);
            if (h > bestH) { bestH = h; bestIdx = idx; bestCs = run1; }
        }
    }

    // wave argmax reduce (max h, first index on ties)
#pragma unroll
    for (int off = 32; off > 0; off >>= 1) {
        const double oH   = __shfl_down(bestH, off, 64);
        const int    oIdx = __shfl_down(bestIdx, off, 64);
        const double oCs  = __shfl_down(bestCs, off, 64);
        if (oH > bestH || (oH == bestH && oIdx < bestIdx)) {
            bestH = oH; bestIdx = oIdx; bestCs = oCs;
        }
    }
    if (lane == 0) { redH[wv] = bestH; redIdx[wv] = bestIdx; redCs[wv] = bestCs; }
    __syncthreads();

    if (tid == 0) {
        double bH = redH[0], bCs = redCs[0];
        int bIdx = redIdx[0];
        for (int w = 1; w < 16; ++w) {
            if (redH[w] > bH || (redH[w] == bH && redIdx[w] < bIdx)) {
                bH = redH[w]; bIdx = redIdx[w]; bCs = redCs[w];
            }
        }
        const double Sb     = total2 - total1 * total1 / nf;
        const double optObj = (total2 - bH) / Sb;
        const double T      = (double)(bIdx + 1);
        out[0] = (float)(bCs / T + LAMB * optObj);
    }
}

// ---------------------------------------------------------------------------
extern "C" void kernel_launch(void* const* d_in, const int* in_sizes, int n_in,
                              void* d_out, int out_size, void* d_ws, size_t ws_size,
                              hipStream_t stream) {
    const float* inp = (const float*)d_in[0];
    const float* tgt = (const float*)d_in[1];
    float* errbuf = (float*)d_ws;   // 8192 f32 = 32 KB scratch

    rowerr_kernel<<<NROWS, 256, 0, stream>>>(inp, tgt, errbuf);
    drae_kernel<<<1, 1024, 0, stream>>>(errbuf, (float*)d_out);
}